// Round 4
// baseline (143.893 us; speedup 1.0000x reference)
//
#include <hip/hip_runtime.h>
#include <math.h>

// N=65536 rows, D=256 fp32. out = sum_i (counts_i - 1)*d_i + exp(d_i)
// d_i = dot(z_a[i], z_b[i]); counts_i-1 = n-3 (i < n-1), n-2 (i == n-1).
//
// History: R1-R6 VGPR-staged loads ~44 us (allocator collapsed batches,
// VGPR 40-52). R7 gload_lds burst ~43 us (vmcnt drained per 16 KB).
// R8 "counted vmcnt" gload_lds pipeline ~42 us: the C++ ds_reads alias
// the in-flight gload_lds LDS writes, so the compiler inserted its own
// vmcnt(0) before them -- the counted wait never took effect. VALUBusy
// 3.8% == pure-stall arithmetic; fillBuffer at 6.6 TB/s in the same
// profile proves the memory system has headroom.
// R9: full inline-asm register pipeline. global_load_dwordx4 into
// asm-pinned ext-vector regs (allocator can't collapse), counted
// s_waitcnt vmcnt(8) + sched_barrier(0) (rule #18), double-buffered
// 4-row batches: 16 KB in flight per wave continuously, no LDS on the
// load path. End-of-wave LDS-transpose reduction kept from R6 (verified).

#define D_DIM 256
#define ROWS_PER_WAVE 16
#define WAVES_PER_BLOCK 4
// blocks = 65536 / (16*4) = 1024; no big LDS -> 4 blocks/CU (VGPR-limited)

typedef float v4f __attribute__((ext_vector_type(4)));

#define GLOAD(dst, ptr, IMM)                                        \
    asm volatile("global_load_dwordx4 %0, %1, off offset:" #IMM    \
                 : "=v"(dst) : "v"(ptr))

#define WAITVM(N) asm volatile("s_waitcnt vmcnt(" #N ")" ::: "memory")
#define SCHED_FENCE() __builtin_amdgcn_sched_barrier(0)

// issue one 4-row batch for both arrays: 8 x 1KB loads, 32 data VGPRs
#define ISSUE(B, pa, pb)                                            \
    GLOAD(a##B##0, pa, 0);    GLOAD(b##B##0, pb, 0);                \
    GLOAD(a##B##1, pa, 1024); GLOAD(b##B##1, pb, 1024);             \
    GLOAD(a##B##2, pa, 2048); GLOAD(b##B##2, pb, 2048);             \
    GLOAD(a##B##3, pa, 3072); GLOAD(b##B##3, pb, 3072)

#define CONSUME(B, q)                                               \
    p[q + 0] = dot4(a##B##0, b##B##0);                              \
    p[q + 1] = dot4(a##B##1, b##B##1);                              \
    p[q + 2] = dot4(a##B##2, b##B##2);                              \
    p[q + 3] = dot4(a##B##3, b##B##3)

__device__ __forceinline__ float dot4(v4f x, v4f y) {
    float t = x[0] * y[0];
    t = fmaf(x[1], y[1], t);
    t = fmaf(x[2], y[2], t);
    t = fmaf(x[3], y[3], t);
    return t;
}

__global__ __launch_bounds__(256, 4)
void dot_loss_partial(const float4* __restrict__ za4,
                      const float4* __restrict__ zb4,
                      float* __restrict__ partial,
                      int n) {
    const int lane = threadIdx.x & 63;
    const int wave = threadIdx.x >> 6;
    const int row0 = (blockIdx.x * WAVES_PER_BLOCK + wave) * ROWS_PER_WAVE;

    // per-lane global base: lane l covers bytes [16l, 16l+16) of each row
    const char* pa = (const char*)(za4 + (size_t)row0 * 64 + lane);
    const char* pb = (const char*)(zb4 + (size_t)row0 * 64 + lane);

    v4f a00, a01, a02, a03, b00, b01, b02, b03;  // buffer 0
    v4f a10, a11, a12, a13, b10, b11, b12, b13;  // buffer 1
    float p[ROWS_PER_WAVE];

    // Software pipeline over 4 batches (4 rows x 2 arrays = 8 KB each).
    // After each ISSUE, 16 loads outstanding; vmcnt(8) = previous batch
    // landed, current batch still in flight. Never 0 until the tail.
    ISSUE(0, pa, pb);
    ISSUE(1, pa + 4096, pb + 4096);
    WAITVM(8); SCHED_FENCE();
    CONSUME(0, 0);
    ISSUE(0, pa + 8192, pb + 8192);
    WAITVM(8); SCHED_FENCE();
    CONSUME(1, 4);
    ISSUE(1, pa + 12288, pb + 12288);
    WAITVM(8); SCHED_FENCE();
    CONSUME(0, 8);
    WAITVM(0); SCHED_FENCE();
    CONSUME(1, 12);

    // End-of-wave transpose reduction (R6-verified pattern).
    // part[wave][r][lane], stride 65: write banks (r+lane)%32 2-way;
    // transpose-read banks (rowIdx + 16*(lane>>4) + c)%32 2-way. Free.
    __shared__ float part[WAVES_PER_BLOCK][ROWS_PER_WAVE][65];
    #pragma unroll
    for (int r = 0; r < ROWS_PER_WAVE; ++r)
        part[wave][r][lane] = p[r];
    __builtin_amdgcn_s_waitcnt(0);  // wave-local LDS RAW drain

    const int rowIdx = lane & 15;
    const int colBase = (lane >> 4) * 16;
    float s = 0.0f;
    #pragma unroll
    for (int c = 0; c < 16; ++c)
        s += part[wave][rowIdx][colBase + c];

    // Merge the 4 quarter-sums; lanes 0..15 end with the full dot d.
    s += __shfl_down(s, 32);
    s += __shfl_down(s, 16);

    float acc = 0.0f;
    if (lane < 16) {
        const int row = row0 + rowIdx;
        const float coeff = (row == n - 1) ? (float)(n - 2) : (float)(n - 3);
        acc = coeff * s + expf(s);
    }
    #pragma unroll
    for (int off = 8; off > 0; off >>= 1)
        acc += __shfl_down(acc, off);

    __shared__ float smem[WAVES_PER_BLOCK];
    if (lane == 0) smem[wave] = acc;
    __syncthreads();
    if (threadIdx.x == 0) {
        float s2 = 0.0f;
        #pragma unroll
        for (int w = 0; w < WAVES_PER_BLOCK; ++w) s2 += smem[w];
        partial[blockIdx.x] = s2;
    }
}

__global__ __launch_bounds__(256)
void reduce_partials(const float* __restrict__ partial,
                     float* __restrict__ out,
                     int m) {
    const int lane = threadIdx.x & 63;
    const int wave = threadIdx.x >> 6;
    double s = 0.0;
    for (int i = threadIdx.x; i < m; i += 256)
        s += (double)partial[i];
    #pragma unroll
    for (int off = 32; off > 0; off >>= 1)
        s += __shfl_down(s, off);
    __shared__ double smem[4];
    if (lane == 0) smem[wave] = s;
    __syncthreads();
    if (threadIdx.x == 0)
        out[0] = (float)(smem[0] + smem[1] + smem[2] + smem[3]);
}

extern "C" void kernel_launch(void* const* d_in, const int* in_sizes, int n_in,
                              void* d_out, int out_size, void* d_ws, size_t ws_size,
                              hipStream_t stream) {
    const float4* za4 = (const float4*)d_in[0];
    const float4* zb4 = (const float4*)d_in[1];
    float* out = (float*)d_out;
    float* partial = (float*)d_ws;
    const int n = in_sizes[0] / D_DIM;
    const int blocks = n / (ROWS_PER_WAVE * WAVES_PER_BLOCK);  // 1024

    dot_loss_partial<<<blocks, 256, 0, stream>>>(za4, zb4, partial, n);
    reduce_partials<<<1, 256, 0, stream>>>(partial, out, blocks);
}